// Round 1
// baseline (367.236 us; speedup 1.0000x reference)
//
#include <hip/hip_runtime.h>
#include <hip/hip_bf16.h>

#define NB 4
#define CB 64
#define HB 256
#define WB 256
#define OB 18
#define HWB (HB*WB)
#define TILE 16
#define ICC 4
#define EPSV 1e-5f

__device__ __forceinline__ int reflect_idx(int i, int n) {
    if (i < 0) i = -i;
    if (i >= n) i = 2*n - 2 - i;
    return i;
}

// Kernel 1: 3x3x64->18 conv on reflect-padded y, + per-block sum/sumsq partials.
__global__ __launch_bounds__(256) void conv_stats_kernel(
    const float* __restrict__ y, const float* __restrict__ w,
    float* __restrict__ sigma, float* __restrict__ psum, float* __restrict__ psq)
{
    __shared__ float tile[ICC][18*18];
    __shared__ float red[4][36];
    const int tid = threadIdx.x;
    const int tx = tid & 15, ty = tid >> 4;
    const int bx = blockIdx.x, by = blockIdx.y, n = blockIdx.z;
    const int h0 = by * TILE, w0 = bx * TILE;

    float acc[OB];
#pragma unroll
    for (int o = 0; o < OB; ++o) acc[o] = 0.f;

    for (int cb = 0; cb < CB; cb += ICC) {
        // stage ICC channels of the 18x18 halo tile (reflect at borders)
        for (int idx = tid; idx < ICC*324; idx += 256) {
            int c   = idx / 324;
            int rem = idx - c*324;
            int r   = rem / 18;
            int col = rem - r*18;
            int gh = reflect_idx(h0 - 1 + r,  HB);
            int gw = reflect_idx(w0 - 1 + col, WB);
            tile[c][r*18 + col] = y[((n*CB + cb + c)*HB + gh)*WB + gw];
        }
        __syncthreads();
#pragma unroll
        for (int ii = 0; ii < ICC; ++ii) {
            float v[9];
#pragma unroll
            for (int dy = 0; dy < 3; ++dy)
#pragma unroll
                for (int dx = 0; dx < 3; ++dx)
                    v[dy*3+dx] = tile[ii][(ty+dy)*18 + tx+dx];
            // weights: wave-uniform indices -> scalar loads
            const float* wp = w + (cb + ii)*9;
#pragma unroll
            for (int o = 0; o < OB; ++o) {
                const float* wo = wp + o*CB*9;
#pragma unroll
                for (int k = 0; k < 9; ++k)
                    acc[o] = fmaf(v[k], wo[k], acc[o]);
            }
        }
        __syncthreads();
    }

    const int q = (h0 + ty)*WB + (w0 + tx);
#pragma unroll
    for (int o = 0; o < OB; ++o)
        sigma[(n*OB + o)*HWB + q] = acc[o];

    // block reduction of sum / sumsq per output channel
    const int lane = tid & 63, wv = tid >> 6;
#pragma unroll
    for (int o = 0; o < OB; ++o) {
        float s  = acc[o];
        float s2 = acc[o]*acc[o];
        for (int off = 32; off > 0; off >>= 1) {
            s  += __shfl_down(s,  off, 64);
            s2 += __shfl_down(s2, off, 64);
        }
        if (lane == 0) { red[wv][o] = s; red[wv][o + OB] = s2; }
    }
    __syncthreads();
    if (tid < 36) {
        float t = red[0][tid] + red[1][tid] + red[2][tid] + red[3][tid];
        const int bid = (n*16 + by)*16 + bx;   // 1024 blocks
        if (tid < OB) psum[tid*1024 + bid] = t;
        else          psq[(tid-OB)*1024 + bid] = t;
    }
}

// Kernel 2: reduce 1024 partials per channel -> fused scale/shift
__global__ __launch_bounds__(256) void stats_kernel(
    const float* __restrict__ psum, const float* __restrict__ psq,
    const float* __restrict__ gamma, const float* __restrict__ beta,
    float* __restrict__ scale, float* __restrict__ shift)
{
    const int o = blockIdx.x;
    const int t = threadIdx.x;
    float s = 0.f, s2 = 0.f;
#pragma unroll
    for (int i = 0; i < 4; ++i) {
        s  += psum[o*1024 + t + i*256];
        s2 += psq [o*1024 + t + i*256];
    }
    for (int off = 32; off > 0; off >>= 1) {
        s  += __shfl_down(s,  off, 64);
        s2 += __shfl_down(s2, off, 64);
    }
    __shared__ float red[8];
    const int lane = t & 63, wv = t >> 6;
    if (lane == 0) { red[wv] = s; red[wv + 4] = s2; }
    __syncthreads();
    if (t == 0) {
        float S  = red[0] + red[1] + red[2] + red[3];
        float SS = red[4] + red[5] + red[6] + red[7];
        const float cnt = (float)(NB * HWB);
        float mean = S / cnt;
        float var  = SS / cnt - mean*mean;
        float sc = gamma[o] * rsqrtf(var + EPSV);
        scale[o] = sc;
        shift[o] = beta[o] - mean * sc;
    }
}

// Kernel 3: normalize + softmax over 18, write v_map, then adaptive filter -> out
__global__ __launch_bounds__(256) void softmax_apply_kernel(
    const float* __restrict__ y, const float* __restrict__ sigma,
    const float* __restrict__ scale, const float* __restrict__ shift,
    float* __restrict__ out)
{
    __shared__ float tile[ICC][18*18];
    const int tid = threadIdx.x;
    const int tx = tid & 15, ty = tid >> 4;
    const int bx = blockIdx.x, by = blockIdx.y, n = blockIdx.z;
    const int h0 = by * TILE, w0 = bx * TILE;
    const int q = (h0 + ty)*WB + (w0 + tx);

    float z[OB];
#pragma unroll
    for (int o = 0; o < OB; ++o)
        z[o] = fmaf(sigma[(n*OB + o)*HWB + q], scale[o], shift[o]);

    float m = z[0];
#pragma unroll
    for (int o = 1; o < OB; ++o) m = fmaxf(m, z[o]);
    float sum = 0.f;
#pragma unroll
    for (int o = 0; o < OB; ++o) { z[o] = __expf(z[o] - m); sum += z[o]; }
    const float r = 1.f / sum;

    float* vmap = out + (size_t)NB*CB*HWB;
#pragma unroll
    for (int o = 0; o < OB; ++o) {
        z[o] *= r;
        vmap[(n*OB + o)*HWB + q] = z[o];
    }

    // apply: out[n,c,q] = sum_k y_reflect[n,c,tap k] * z[group(c)*9 + k]
#pragma unroll
    for (int g = 0; g < 2; ++g) {          // unrolled -> z indices compile-time
        for (int cb = g*32; cb < g*32 + 32; cb += ICC) {
            for (int idx = tid; idx < ICC*324; idx += 256) {
                int c   = idx / 324;
                int rem = idx - c*324;
                int rr  = rem / 18;
                int col = rem - rr*18;
                int gh = reflect_idx(h0 - 1 + rr,  HB);
                int gw = reflect_idx(w0 - 1 + col, WB);
                tile[c][rr*18 + col] = y[((n*CB + cb + c)*HB + gh)*WB + gw];
            }
            __syncthreads();
#pragma unroll
            for (int ii = 0; ii < ICC; ++ii) {
                float a = 0.f;
#pragma unroll
                for (int dy = 0; dy < 3; ++dy)
#pragma unroll
                    for (int dx = 0; dx < 3; ++dx)
                        a = fmaf(tile[ii][(ty+dy)*18 + tx+dx], z[g*9 + dy*3 + dx], a);
                out[((n*CB + cb + ii)*HWB) + q] = a;
            }
            __syncthreads();
        }
    }
}

extern "C" void kernel_launch(void* const* d_in, const int* in_sizes, int n_in,
                              void* d_out, int out_size, void* d_ws, size_t ws_size,
                              hipStream_t stream) {
    const float* y     = (const float*)d_in[0];
    const float* w     = (const float*)d_in[1];
    const float* gamma = (const float*)d_in[2];
    const float* beta  = (const float*)d_in[3];
    float* out = (float*)d_out;

    float* sigma = (float*)d_ws;                 // 4*18*65536 = 4,718,592 floats
    float* psum  = sigma + (size_t)NB*OB*HWB;    // 18*1024
    float* psq   = psum + OB*1024;               // 18*1024
    float* scale = psq  + OB*1024;               // 18
    float* shift = scale + OB;                   // 18

    dim3 grid(WB/TILE, HB/TILE, NB);   // (16,16,4)
    dim3 block(256);
    conv_stats_kernel<<<grid, block, 0, stream>>>(y, w, sigma, psum, psq);
    stats_kernel<<<dim3(OB), block, 0, stream>>>(psum, psq, gamma, beta, scale, shift);
    softmax_apply_kernel<<<grid, block, 0, stream>>>(y, sigma, scale, shift, out);
}

// Round 2
// 324.856 us; speedup vs baseline: 1.1305x; 1.1305x over previous
//
#include <hip/hip_runtime.h>
#include <hip/hip_bf16.h>

#define NB 4
#define CB 64
#define HB 256
#define WB 256
#define OB 18
#define HWB (HB*WB)
#define TILE 16
#define ICC 8
#define EPSV 1e-5f

__device__ __forceinline__ int reflect_idx(int i, int n) {
    if (i < 0) i = -i;
    if (i >= n) i = 2*n - 2 - i;
    return i;
}

// Transpose weights (18,64,3,3) -> wt[c][o][k] so the conv reads 162
// contiguous floats per input channel (streaming scalar loads).
__global__ __launch_bounds__(256) void transpose_w_kernel(
    const float* __restrict__ w, float* __restrict__ wt)
{
    int i = blockIdx.x * 256 + threadIdx.x;
    if (i < OB*CB*9) {
        int o   = i / (CB*9);
        int rem = i - o*CB*9;
        int c   = rem / 9;
        int k   = rem - c*9;
        wt[c*OB*9 + o*9 + k] = w[i];
    }
}

// Kernel 1: 3x3x64->18 conv on reflect-padded y, + per-block sum/sumsq partials.
__global__ __launch_bounds__(256) void conv_stats_kernel(
    const float* __restrict__ y, const float* __restrict__ wt,
    float* __restrict__ sigma, float* __restrict__ psum, float* __restrict__ psq)
{
    __shared__ float tile[ICC*324];
    __shared__ float red[4][36];
    const int tid = threadIdx.x;
    const int tx = tid & 15, ty = tid >> 4;
    const int bx = blockIdx.x, by = blockIdx.y, n = blockIdx.z;
    const int h0 = by * TILE, w0 = bx * TILE;

    // Precompute staging map once per block: element j = tid + 256*i of the
    // ICC*324 halo buffer -> (channel-in-chunk, reflected pixel offset).
    int scc[11], soff[11];
#pragma unroll
    for (int i = 0; i < 11; ++i) {
        int j = tid + i*256;
        if (j < ICC*324) {
            int c   = j / 324;
            int rem = j - c*324;
            int r   = rem / 18;
            int col = rem - r*18;
            scc[i]  = c;
            soff[i] = reflect_idx(h0 - 1 + r, HB)*WB + reflect_idx(w0 - 1 + col, WB);
        } else { scc[i] = 0; soff[i] = 0; }
    }

    float acc[OB];
#pragma unroll
    for (int o = 0; o < OB; ++o) acc[o] = 0.f;

    const float* ybase = y + (size_t)n*CB*HWB;

    for (int cb = 0; cb < CB; cb += ICC) {
#pragma unroll
        for (int i = 0; i < 10; ++i)
            tile[tid + i*256] = ybase[(size_t)(cb + scc[i])*HWB + soff[i]];
        if (tid < ICC*324 - 2560)
            tile[tid + 2560] = ybase[(size_t)(cb + scc[10])*HWB + soff[10]];
        __syncthreads();

#pragma unroll
        for (int ii = 0; ii < ICC; ++ii) {
            float v[9];
#pragma unroll
            for (int dy = 0; dy < 3; ++dy)
#pragma unroll
                for (int dx = 0; dx < 3; ++dx)
                    v[dy*3+dx] = tile[ii*324 + (ty+dy)*18 + tx+dx];
            const float* wp = wt + (cb + ii)*162;   // 162 contiguous, uniform
#pragma unroll
            for (int o = 0; o < OB; ++o)
#pragma unroll
                for (int k = 0; k < 9; ++k)
                    acc[o] = fmaf(v[k], wp[o*9 + k], acc[o]);
        }
        __syncthreads();
    }

    const int q = (h0 + ty)*WB + (w0 + tx);
#pragma unroll
    for (int o = 0; o < OB; ++o)
        sigma[((size_t)n*OB + o)*HWB + q] = acc[o];

    const int lane = tid & 63, wv = tid >> 6;
#pragma unroll
    for (int o = 0; o < OB; ++o) {
        float s  = acc[o];
        float s2 = acc[o]*acc[o];
        for (int off = 32; off > 0; off >>= 1) {
            s  += __shfl_down(s,  off, 64);
            s2 += __shfl_down(s2, off, 64);
        }
        if (lane == 0) { red[wv][o] = s; red[wv][o + OB] = s2; }
    }
    __syncthreads();
    if (tid < 36) {
        float t = red[0][tid] + red[1][tid] + red[2][tid] + red[3][tid];
        const int bid = (n*16 + by)*16 + bx;
        if (tid < OB) psum[tid*1024 + bid] = t;
        else          psq[(tid-OB)*1024 + bid] = t;
    }
}

// Kernel 2: reduce 1024 partials per channel -> fused scale/shift
__global__ __launch_bounds__(256) void stats_kernel(
    const float* __restrict__ psum, const float* __restrict__ psq,
    const float* __restrict__ gamma, const float* __restrict__ beta,
    float* __restrict__ scale, float* __restrict__ shift)
{
    const int o = blockIdx.x;
    const int t = threadIdx.x;
    float s = 0.f, s2 = 0.f;
#pragma unroll
    for (int i = 0; i < 4; ++i) {
        s  += psum[o*1024 + t + i*256];
        s2 += psq [o*1024 + t + i*256];
    }
    for (int off = 32; off > 0; off >>= 1) {
        s  += __shfl_down(s,  off, 64);
        s2 += __shfl_down(s2, off, 64);
    }
    __shared__ float red[8];
    const int lane = t & 63, wv = t >> 6;
    if (lane == 0) { red[wv] = s; red[wv + 4] = s2; }
    __syncthreads();
    if (t == 0) {
        float S  = red[0] + red[1] + red[2] + red[3];
        float SS = red[4] + red[5] + red[6] + red[7];
        const float cnt = (float)(NB * HWB);
        float mean = S / cnt;
        float var  = SS / cnt - mean*mean;
        float sc = gamma[o] * rsqrtf(var + EPSV);
        scale[o] = sc;
        shift[o] = beta[o] - mean * sc;
    }
}

// Kernel 3: normalize + softmax over 18, write v_map, then adaptive filter -> out
__global__ __launch_bounds__(256) void softmax_apply_kernel(
    const float* __restrict__ y, const float* __restrict__ sigma,
    const float* __restrict__ scale, const float* __restrict__ shift,
    float* __restrict__ out)
{
    __shared__ float tile[ICC*324];
    const int tid = threadIdx.x;
    const int tx = tid & 15, ty = tid >> 4;
    const int bx = blockIdx.x, by = blockIdx.y, n = blockIdx.z;
    const int h0 = by * TILE, w0 = bx * TILE;
    const int q = (h0 + ty)*WB + (w0 + tx);

    int scc[11], soff[11];
#pragma unroll
    for (int i = 0; i < 11; ++i) {
        int j = tid + i*256;
        if (j < ICC*324) {
            int c   = j / 324;
            int rem = j - c*324;
            int r   = rem / 18;
            int col = rem - r*18;
            scc[i]  = c;
            soff[i] = reflect_idx(h0 - 1 + r, HB)*WB + reflect_idx(w0 - 1 + col, WB);
        } else { scc[i] = 0; soff[i] = 0; }
    }

    float z[OB];
#pragma unroll
    for (int o = 0; o < OB; ++o)
        z[o] = fmaf(sigma[((size_t)n*OB + o)*HWB + q], scale[o], shift[o]);

    float m = z[0];
#pragma unroll
    for (int o = 1; o < OB; ++o) m = fmaxf(m, z[o]);
    float sum = 0.f;
#pragma unroll
    for (int o = 0; o < OB; ++o) { z[o] = __expf(z[o] - m); sum += z[o]; }
    const float r = 1.f / sum;

    float* vmap = out + (size_t)NB*CB*HWB;
#pragma unroll
    for (int o = 0; o < OB; ++o) {
        z[o] *= r;
        vmap[((size_t)n*OB + o)*HWB + q] = z[o];
    }

    const float* ybase = y + (size_t)n*CB*HWB;
    float* obase = out + (size_t)n*CB*HWB;

#pragma unroll
    for (int g = 0; g < 2; ++g) {          // unrolled -> z indices compile-time
        for (int cb = g*32; cb < g*32 + 32; cb += ICC) {
#pragma unroll
            for (int i = 0; i < 10; ++i)
                tile[tid + i*256] = ybase[(size_t)(cb + scc[i])*HWB + soff[i]];
            if (tid < ICC*324 - 2560)
                tile[tid + 2560] = ybase[(size_t)(cb + scc[10])*HWB + soff[10]];
            __syncthreads();
#pragma unroll
            for (int ii = 0; ii < ICC; ++ii) {
                float a = 0.f;
#pragma unroll
                for (int dy = 0; dy < 3; ++dy)
#pragma unroll
                    for (int dx = 0; dx < 3; ++dx)
                        a = fmaf(tile[ii*324 + (ty+dy)*18 + tx+dx], z[g*9 + dy*3 + dx], a);
                obase[(size_t)(cb + ii)*HWB + q] = a;
            }
            __syncthreads();
        }
    }
}

extern "C" void kernel_launch(void* const* d_in, const int* in_sizes, int n_in,
                              void* d_out, int out_size, void* d_ws, size_t ws_size,
                              hipStream_t stream) {
    const float* y     = (const float*)d_in[0];
    const float* w     = (const float*)d_in[1];
    const float* gamma = (const float*)d_in[2];
    const float* beta  = (const float*)d_in[3];
    float* out = (float*)d_out;

    float* sigma = (float*)d_ws;                 // 4*18*65536 floats
    float* wt    = sigma + (size_t)NB*OB*HWB;    // 10368
    float* psum  = wt + OB*CB*9;                 // 18*1024
    float* psq   = psum + OB*1024;               // 18*1024
    float* scale = psq  + OB*1024;               // 18
    float* shift = scale + OB;                   // 18

    dim3 grid(WB/TILE, HB/TILE, NB);   // (16,16,4)
    dim3 block(256);
    transpose_w_kernel<<<dim3((OB*CB*9 + 255)/256), block, 0, stream>>>(w, wt);
    conv_stats_kernel<<<grid, block, 0, stream>>>(y, wt, sigma, psum, psq);
    stats_kernel<<<dim3(OB), block, 0, stream>>>(psum, psq, gamma, beta, scale, shift);
    softmax_apply_kernel<<<grid, block, 0, stream>>>(y, sigma, scale, shift, out);
}